// Round 10
// baseline (201.182 us; speedup 1.0000x reference)
//
#include <hip/hip_runtime.h>
#include <stdint.h>

#define NUM_CLASSES 80u
#define TOPK 1000
#define CONF_T 0.05f
#define NMS_T 0.6f
#define MAX_COORD 4096.0f
#define TARGET 1152u            // top-1000 + tie/superset slack
#define NBLK_A 2048u            // kA grid
#define SLOTS 48u               // candidate slots per kA block (mean 13.8)
#define LINCAP (NBLK_A * SLOTS) // 98304 slots total
#define SRVCAP 2048u            // survivor buffer (>= TARGET + ties)
#define STATIC_F 4.0f           // static candidate prefilter threshold
#define STATIC_KEY 0xC0800000u  // fkey(+4.0f)
#define NBINS 4096              // spread bins: (k - STATIC_KEY) >> 13
#define BINSH 13
#define LCAP 64u                // per-block LDS candidate staging (kA)
#define PBLK 1536u              // per-block survivor staging (kSel slice size)
#define ROWS_PB 63u             // kFG owned ranks per block (16*63=1008>=1000)

typedef unsigned long long ull;
typedef ull ull2 __attribute__((ext_vector_type(2)));

// Monotone float->uint key: descending float == descending key
__device__ __forceinline__ uint32_t fkey(float x) {
  uint32_t k = __float_as_uint(x);
  return (k & 0x80000000u) ? ~k : (k | 0x80000000u);
}

// Inclusive suffix sum of per-thread v across 1024 threads (3 barriers).
// part = LDS[16]; part[0] ends as grand total.
__device__ __forceinline__ uint32_t suffix_scan_1024(uint32_t v, uint32_t* part,
                                                     int t) {
  int lane = t & 63, wid = t >> 6;
#pragma unroll
  for (int off = 1; off < 64; off <<= 1) {
    uint32_t x = __shfl_down(v, off);
    if (lane + off < 64) v += x;
  }
  if (lane == 0) part[wid] = v;  // wave totals
  __syncthreads();
  if (wid == 0) {
    uint32_t pv = (lane < 16) ? part[lane] : 0u;
#pragma unroll
    for (int off = 1; off < 16; off <<= 1) {
      uint32_t x = __shfl_down(pv, off);
      if (lane + off < 16) pv += x;
    }
    if (lane < 16) part[lane] = pv;  // inclusive suffix of wave totals
  }
  __syncthreads();
  uint32_t after = (wid < 15) ? part[wid + 1] : 0u;
  return v + after;
}

// Suffix-scan hl[NBINSX] with 1024 threads, find crossing bin for `target`.
// A = count strictly above bin; cnt = hl[bin]; A < target <= A + cnt.
template <int NBINSX>
__device__ __forceinline__ void pick_bin1024(const uint32_t* hl, uint32_t target,
                                             int t, uint32_t* part,
                                             uint32_t* binS, uint32_t* AS,
                                             uint32_t* cntS) {
  const int CH = NBINSX / 1024;
  uint32_t cc[CH];
  uint32_t s = 0;
#pragma unroll
  for (int j = 0; j < CH; ++j) { cc[j] = hl[t * CH + j]; s += cc[j]; }
  uint32_t incl = suffix_scan_1024(s, part, t);
  uint32_t after = incl - s;  // suffix strictly after my chunk
  if (incl >= target && after < target) {  // crossing in my chunk: unique
    uint32_t cum = after;
    for (int j = CH - 1; j >= 0; --j) {
      if (cum + cc[j] >= target) {
        *binS = (uint32_t)(t * CH + j); *AS = cum; *cntS = cc[j]; break;
      }
      cum += cc[j];
    }
  }
}

// ---------------- kernel A: slotted stream + static compact ---------------
// Slotted output (per-block 48-slot region, plain cnt[b] store, pad keys 0)
// needs NO zeroed global counter. Block 0 zeroes sel[] for kSel's survivor
// atomic. Overflow (cnt[b] > SLOTS) detected by kSel -> full-rescan fallback.
__global__ void __launch_bounds__(256) kA(const float4* __restrict__ cls, int n4,
                                          uint32_t* __restrict__ sel,
                                          uint32_t* __restrict__ cnt,
                                          uint32_t* __restrict__ candKey,
                                          uint32_t* __restrict__ candIdx) {
  __shared__ uint32_t lk[LCAP];
  __shared__ uint32_t li[LCAP];
  __shared__ uint32_t lcnt;
  if (threadIdx.x == 0) lcnt = 0u;
  if (blockIdx.x == 0 && threadIdx.x < 16) sel[threadIdx.x] = 0u;
  __syncthreads();
  int stride = gridDim.x * blockDim.x;
  for (int i = blockIdx.x * blockDim.x + threadIdx.x; i < n4; i += stride) {
    float4 v = cls[i];
    float f4[4] = {v.x, v.y, v.z, v.w};
#pragma unroll
    for (int c = 0; c < 4; ++c) {
      if (f4[c] >= STATIC_F) {
        uint32_t p = atomicAdd(&lcnt, 1u);  // LDS atomic: cheap, distributed
        if (p < LCAP) { lk[p] = fkey(f4[c]); li[p] = (uint32_t)i * 4u + c; }
        // p >= LCAP: dropped, but cnt[b] records the truth -> fallback
      }
    }
  }
  __syncthreads();
  uint32_t c = lcnt;
  if (threadIdx.x == 0) cnt[blockIdx.x] = c;  // raw count; >SLOTS => overflow
  uint32_t m = c; if (m > SLOTS) m = SLOTS;
  uint32_t base = blockIdx.x * SLOTS;
  for (uint32_t i = threadIdx.x; i < SLOTS; i += 256u)
    candKey[base + i] = (i < m) ? lk[i] : 0u;   // pad keys filterable (<T)
  for (uint32_t i = threadIdx.x; i < m; i += 256u)
    candIdx[base + i] = li[i];
}

// ---------------- kernel Sel: multi-block threshold + survivor select -----
// 64 blocks x 1024 threads. Each block: read cnt[] (total+overflow),
// redundant 4096-bin LDS hist over the slot keys (24 uint4 iters, pads
// filtered), pick crossing bin, T = bin floor (TARGET slack absorbs the
// bin; bump to bin+1 on tie-spike -- block 0 then prefills), select own
// 1536-slot slice into LDS, ONE global atomic, emit srv.
// FALLBACK (overflow or total < TARGET; never on bench data): block 0 full
// 21M two-level scan + prefill + select.
__global__ void __launch_bounds__(1024) kSel(
    const float4* __restrict__ cls4, int n4,
    uint32_t* __restrict__ sel, const uint32_t* __restrict__ cnt,
    const uint32_t* __restrict__ candKey, const uint32_t* __restrict__ candIdx,
    ull* __restrict__ srv, float* __restrict__ out,
    float* __restrict__ topScore) {
  __shared__ uint32_t hl[NBINS];       // 16 KB
  __shared__ uint32_t part[16];
  __shared__ uint32_t sk_[PBLK];       // staged survivor keys (6 KB)
  __shared__ uint32_t si_[PBLK];       // staged survivor idxs (6 KB)
  __shared__ uint32_t lcnt, gbase, binS, AS, cntS, ovS;
  int t = threadIdx.x;
  uint32_t b = blockIdx.x;

  uint32_t c0 = cnt[t], c1 = cnt[t + 1024];
  if (t == 0) { lcnt = 0u; binS = 0u; AS = 0u; cntS = 0u; ovS = 0u; }
  for (int i = t; i < NBINS; i += 1024) hl[i] = 0u;
  __syncthreads();
  if (c0 > SLOTS || c1 > SLOTS) atomicOr(&ovS, 1u);
  uint32_t m0 = c0 > SLOTS ? SLOTS : c0, m1 = c1 > SLOTS ? SLOTS : c1;
  (void)suffix_scan_1024(m0 + m1, part, t);      // part[0] = total (barriers
  uint32_t total = part[0];                      //  also publish ovS)
  bool fb = (ovS != 0u) || (total < TARGET);

  if (!fb) {
    // ---- redundant hist over slot keys (coalesced, pads filtered) ----
    const uint4* ck4 = (const uint4*)candKey;
    for (uint32_t i = t; i < LINCAP / 4u; i += 1024u) {
      uint4 kv = ck4[i];
      uint32_t kk[4] = {kv.x, kv.y, kv.z, kv.w};
#pragma unroll
      for (int q = 0; q < 4; ++q) {
        uint32_t k = kk[q];
        if (k >= STATIC_KEY) {
          uint32_t bb = (k - STATIC_KEY) >> BINSH;
          if (bb > NBINS - 1u) bb = NBINS - 1u;
          atomicAdd(&hl[bb], 1u);
        }
      }
    }
    __syncthreads();
    pick_bin1024<NBINS>(hl, TARGET, t, part, &binS, &AS, &cntS);
    __syncthreads();
    bool bump = (AS + cntS > SRVCAP);  // tie-spike (adversarial only)
    uint32_t T = STATIC_KEY + ((binS + (bump ? 1u : 0u)) << BINSH);
    if (bump && b == 0) {              // scount may drop below TOPK: prefill
      for (int i = t; i < 4000; i += 1024) out[i] = 0.0f;
      for (int i = t; i < 1000; i += 1024) { out[5000 + i] = 0.0f; topScore[i] = 0.0f; }
    }
    // ---- select own contiguous slice of slots ----
    uint32_t lo = b * (LINCAP / 64u), hi = lo + (LINCAP / 64u);  // 1536
    for (uint32_t i = lo + t; i < hi; i += 1024u) {
      uint32_t k = candKey[i];
      if (k >= T) {                    // pads (0) auto-excluded
        uint32_t p = atomicAdd(&lcnt, 1u);
        sk_[p] = k; si_[p] = candIdx[i];  // p < PBLK == slice size: safe
      }
    }
    __syncthreads();
    uint32_t c = lcnt;
    if (t == 0 && c) gbase = atomicAdd(&sel[4], c);  // ONE per block
    __syncthreads();
    for (uint32_t i = t; i < c; i += 1024u) {
      uint32_t k = sk_[i];
      float x = __uint_as_float(k & 0x7fffffffu);  // candidates all positive
      float p = 1.0f / (1.0f + expf(-x));          // fp32 sigmoid
      uint32_t pos = gbase + i;
      if (pos < SRVCAP)
        srv[pos] = ((ull)__float_as_uint(p) << 32) | (ull)(uint32_t)(~si_[i]);
    }
  } else {
    if (b != 0) return;
    // ---- single-block full fallback (perf-irrelevant) ----
    for (int i = t; i < NBINS; i += 1024) hl[i] = 0u;
    if (t == 0) { binS = 0u; AS = 0u; cntS = 0u; }
    __syncthreads();
    for (int i = t; i < n4; i += 1024) {
      float4 v = cls4[i];
      atomicAdd(&hl[fkey(v.x) >> 20], 1u);
      atomicAdd(&hl[fkey(v.y) >> 20], 1u);
      atomicAdd(&hl[fkey(v.z) >> 20], 1u);
      atomicAdd(&hl[fkey(v.w) >> 20], 1u);
    }
    __syncthreads();
    pick_bin1024<NBINS>(hl, TARGET, t, part, &binS, &AS, &cntS);  // k>>20
    __syncthreads();
    uint32_t b20 = binS, A = AS;
    hl[t] = 0u;
    if (t == 0) binS = 0u;
    __syncthreads();
    for (int i = t; i < n4; i += 1024) {  // fine 10-bit hist within b20
      float4 v = cls4[i];
      uint32_t k4[4] = {fkey(v.x), fkey(v.y), fkey(v.z), fkey(v.w)};
#pragma unroll
      for (int c2 = 0; c2 < 4; ++c2)
        if ((k4[c2] >> 20) == b20) atomicAdd(&hl[(k4[c2] >> 10) & 1023u], 1u);
    }
    __syncthreads();
    uint32_t rem = TARGET - A;  // >= 1; fine total >= rem
    pick_bin1024<1024>(hl, rem, t, part, &binS, &AS, &cntS);
    __syncthreads();
    uint32_t T = (b20 << 20) | (binS << 10);
    for (int i = t; i < 4000; i += 1024) out[i] = 0.0f;   // prefill
    for (int i = t; i < 1000; i += 1024) { out[5000 + i] = 0.0f; topScore[i] = 0.0f; }
    for (int i = t; i < n4; i += 1024) {
      float4 v = cls4[i];
      uint32_t k4[4] = {fkey(v.x), fkey(v.y), fkey(v.z), fkey(v.w)};
#pragma unroll
      for (int c2 = 0; c2 < 4; ++c2) {
        uint32_t k = k4[c2];
        if (k >= T) {
          uint32_t pos = atomicAdd(&sel[4], 1u);
          if (pos < SRVCAP) {
            float x = (k & 0x80000000u) ? __uint_as_float(k & 0x7fffffffu)
                                        : __uint_as_float(~k);
            float p = 1.0f / (1.0f + expf(-x));
            uint32_t idx = (uint32_t)i * 4u + c2;
            srv[pos] = ((ull)__float_as_uint(p) << 32) | (ull)(uint32_t)(~idx);
          }
        }
      }
    }
  }
}

// ---------------- kernel FG: fused rank + emit + IoU masks ----------------
// r9 polish: kF2(8 blk) + obox handoff + kG(1000 blk) collapse into 16
// blocks x 1024. Each block redundantly: stage srv (16 KB LDS), full
// cooperative rank (2 survivors/thread x 576 broadcast ull2 LDS reads),
// fetch the <=1000 ranked boxes (+class offset) into LDS, then emit
// outputs AND compute IoU mask rows ONLY for its 63 owned ranks
// (1 word-task/thread x 64 serial IoUs). Removes one dispatch + the obox
// global round-trip. rowsum[r] written for ALL owned r (0 for r>=scount).
__global__ void __launch_bounds__(1024) kFG(
    const float* __restrict__ box, const int* __restrict__ ph,
    const int* __restrict__ pw, const uint32_t* __restrict__ sel,
    const ull* __restrict__ srv, float* __restrict__ out,
    float* __restrict__ topScore, ull* __restrict__ masks,
    uint32_t* __restrict__ rowsum) {
  __shared__ __align__(16) ull sk[SRVCAP];      // 16 KB survivors
  __shared__ float ob[TOPK][4];                 // 16 KB ranked+offset boxes
  __shared__ uint32_t rkslot[TOPK];             // 4 KB rank -> slot|label<<16
  __shared__ uint32_t rs[ROWS_PB];              // per-owned-row word flags
  int t = threadIdx.x;
  uint32_t b = blockIdx.x;
  uint32_t scount = sel[4]; if (scount > SRVCAP) scount = SRVCAP;
  uint32_t pad = (scount + 1u) & ~1u;
  for (uint32_t i = t; i < pad; i += 1024u) sk[i] = (i < scount) ? srv[i] : 0ull;
  if (t < (int)ROWS_PB) rs[t] = 0u;
  __syncthreads();
  // ---- full cooperative rank (keys unique -> ranks are a permutation) ----
  for (uint32_t s = t; s < scount; s += 1024u) {
    ull my = sk[s];
    uint32_t rank = 0;
    for (uint32_t j = 0; j < pad; j += 2u) {
      ull2 v = *reinterpret_cast<const ull2*>(&sk[j]);  // broadcast read
      rank += (v.x > my) + (v.y > my);
    }
    if (rank < TOPK) rkslot[rank] = s;          // s < 2048: low 16 bits
  }
  __syncthreads();
  // ---- fetch ranked boxes (+class offset) into LDS; pack label ----
  float W = (float)pw[0], H = (float)ph[0];
  uint32_t nrank = scount < TOPK ? scount : TOPK;
  for (uint32_t r = t; r < nrank; r += 1024u) {
    uint32_t s = rkslot[r];
    uint32_t idx = ~(uint32_t)sk[s];
    uint32_t label = idx % NUM_CLASSES;
    uint32_t anchor = idx / NUM_CLASSES;
    float off = (float)label * MAX_COORD;       // class-aware NMS offset
    ob[r][0] = box[anchor * 4u + 0u] + off;
    ob[r][1] = box[anchor * 4u + 1u] + off;
    ob[r][2] = box[anchor * 4u + 2u] + off;
    ob[r][3] = box[anchor * 4u + 3u] + off;
    rkslot[r] = s | (label << 16);
  }
  __syncthreads();
  uint32_t r0 = b * ROWS_PB;
  uint32_t r1 = r0 + ROWS_PB; if (r1 > TOPK) r1 = TOPK;
  // ---- emit outputs for owned ranks ----
  for (uint32_t r = r0 + (uint32_t)t; r < r1; r += 1024u) {
    if (r < nrank) {
      uint32_t sl = rkslot[r];
      uint32_t s = sl & 0xFFFFu;
      uint32_t label = sl >> 16;
      float off = (float)label * MAX_COORD;
      float p = __uint_as_float((uint32_t)(sk[s] >> 32));
      out[r * 4 + 0] = fminf(fmaxf((ob[r][0] - off) / W, 0.0f), 1.0f);
      out[r * 4 + 1] = fminf(fmaxf((ob[r][1] - off) / H, 0.0f), 1.0f);
      out[r * 4 + 2] = fminf(fmaxf((ob[r][2] - off) / W, 0.0f), 1.0f);
      out[r * 4 + 3] = fminf(fmaxf((ob[r][3] - off) / H, 0.0f), 1.0f);
      out[5000 + r] = (float)label;
      topScore[r] = p;
    }
    // r >= nrank: prefilled by kSel's bump/fallback paths (only paths where
    // scount can be < TOPK)
  }
  // ---- IoU mask words for owned rows: 1 task/thread, 64 serial IoUs ----
  uint32_t ntask = (r1 - r0) * 16u;
  for (uint32_t task = t; task < ntask; task += 1024u) {
    uint32_t rl = task >> 4, w = task & 15u;
    uint32_t r = r0 + rl;
    ull m = 0ull;
    if (r < nrank) {
      float x1i = ob[r][0], y1i = ob[r][1], x2i = ob[r][2], y2i = ob[r][3];
      float ai = (x2i - x1i) * (y2i - y1i);
      uint32_t jhi = w * 64u + 64u; if (jhi > nrank) jhi = nrank;
      for (uint32_t j = w * 64u; j < jhi; ++j) {
        if (j <= r) continue;                   // row r suppresses only j > r
        float x1j = ob[j][0], y1j = ob[j][1], x2j = ob[j][2], y2j = ob[j][3];
        float aj = (x2j - x1j) * (y2j - y1j);
        float ix1 = fmaxf(x1i, x1j), iy1 = fmaxf(y1i, y1j);
        float ix2 = fminf(x2i, x2j), iy2 = fminf(y2i, y2j);
        float iw = fmaxf(ix2 - ix1, 0.0f), ih = fmaxf(iy2 - iy1, 0.0f);
        float inter = iw * ih;
        float iou = inter / (ai + aj - inter + 1e-9f);
        if (iou > NMS_T) m |= 1ull << (j & 63u);
      }
    }
    masks[r * 16 + w] = m;
    if (m) atomicOr(&rs[rl], 1u << w);
  }
  __syncthreads();
  if (t < (int)(r1 - r0)) rowsum[r0 + t] = rs[t];
}

// ---------------- kernel H: LDS-staged single-wave greedy NMS -------------
// 1024 threads; stages only rowsum-flagged mask words.
__global__ void __launch_bounds__(1024) kH(const float* __restrict__ topScore,
                                           const ull* __restrict__ masks,
                                           const uint32_t* __restrict__ rowsum,
                                           float* __restrict__ out) {
  __shared__ ull lmask[TOPK * 16];
  __shared__ uint32_t rsL[TOPK];
  __shared__ ull keepsh[16];
  int t = threadIdx.x;
  if (t < TOPK) rsL[t] = rowsum[t];
  if (t < 16) keepsh[t] = 0ull;
  __syncthreads();
  for (int i = t; i < TOPK * 16; i += 1024)  // stage only nonzero words
    lmask[i] = ((rsL[i >> 4] >> (i & 15)) & 1u) ? masks[i] : 0ull;
  {
    bool v = (t < TOPK) && (topScore[t] > CONF_T);
    ull bb = __ballot(v);
    if ((t & 63) == 0) keepsh[t >> 6] = bb;
  }
  __syncthreads();
  if (t < 64) {  // single-wave greedy loop, no barriers inside
    ull kw = (t < 16) ? keepsh[t] : 0ull;
    ull nzw = 0ull;
    if (t < 16) {
      for (int b = 0; b < 64; ++b) {
        int r = t * 64 + b;
        if (r < TOPK && rsL[r]) nzw |= 1ull << b;
      }
    }
    for (int w = 0; w < 16; ++w) {
      ull cur = __shfl(kw, w) & __shfl(nzw, w);
      while (cur) {
        int b = __ffsll((long long)cur) - 1;
        int i = w * 64 + b;
        if (t < 16) kw &= ~lmask[i * 16 + t];  // row i suppresses only j > i
        ull nk = __shfl(kw, w);
        cur = nk & __shfl(nzw, w);
        cur &= (b == 63) ? 0ull : (~0ull << (b + 1));
      }
    }
    if (t < 16) keepsh[t] = kw;
  }
  __syncthreads();
  if (t < TOPK) {
    bool k = (keepsh[t >> 6] >> (t & 63)) & 1ull;
    float s = topScore[t];
    out[4000 + t] = k ? s : 0.0f;
    out[6000 + t] = k ? 1.0f : 0.0f;
  }
}

extern "C" void kernel_launch(void* const* d_in, const int* in_sizes, int n_in,
                              void* d_out, int out_size, void* d_ws, size_t ws_size,
                              hipStream_t stream) {
  const float* cls = (const float*)d_in[0];  // (1, N, 80) logits
  const float* box = (const float*)d_in[1];  // (1, N, 4)
  const int* ph = (const int*)d_in[2];       // img_h
  const int* pw = (const int*)d_in[3];       // img_w
  float* out = (float*)d_out;                // [boxes 4000 | scores 1000 | labels 1000 | keep 1000]
  int n = in_sizes[0];                       // 20,971,520 (divisible by 4)

  uint8_t* w = (uint8_t*)d_ws;
  uint32_t* cnt     = (uint32_t*)(w);                               // 8 KB
  uint32_t* sel     = (uint32_t*)(w + 8192);                        // 64 B (pad 4 KB)
  uint32_t* candKey = (uint32_t*)(w + 12288);                       // 384 KB
  uint32_t* candIdx = (uint32_t*)(w + 12288 + (size_t)LINCAP * 4);  // 384 KB
  ull*      srv     = (ull*)     (w + 12288 + (size_t)LINCAP * 8);  // 16 KB
  float*    topScore= (float*)   (w + 12288 + (size_t)LINCAP * 8 + 16384);          // 4 KB
  ull*      masks   = (ull*)     (w + 12288 + (size_t)LINCAP * 8 + 16384 + 4096);   // 128 KB
  uint32_t* rowsum  = (uint32_t*)(w + 12288 + (size_t)LINCAP * 8 + 16384 + 4096 + 131072); // 4 KB

  kA  <<<NBLK_A, 256, 0, stream>>>((const float4*)cls, n / 4, sel, cnt, candKey, candIdx);
  kSel<<<64, 1024, 0, stream>>>((const float4*)cls, n / 4, sel, cnt, candKey, candIdx, srv, out, topScore);
  kFG <<<16, 1024, 0, stream>>>(box, ph, pw, sel, srv, out, topScore, masks, rowsum);
  kH  <<<1, 1024, 0, stream>>>(topScore, masks, rowsum, out);
}

// Round 11
// 168.182 us; speedup vs baseline: 1.1962x; 1.1962x over previous
//
#include <hip/hip_runtime.h>
#include <stdint.h>

#define NUM_CLASSES 80u
#define TOPK 1000
#define CONF_T 0.05f
#define NMS_T 0.6f
#define MAX_COORD 4096.0f
#define TARGET 1152u            // top-1000 + tie/superset slack
#define NBLK_A 2048u            // kA grid
#define SLOTS 48u               // candidate slots per kA block (mean 13.8)
#define LINCAP (NBLK_A * SLOTS) // 98304 slots total
#define SRVCAP 2048u            // survivor buffer (>= TARGET + ties)
#define STATIC_F 4.0f           // static candidate prefilter threshold
#define STATIC_KEY 0xC0800000u  // fkey(+4.0f)
#define NBINS 4096              // spread bins: (k - STATIC_KEY) >> 13
#define BINSH 13
#define LCAP 64u                // per-block LDS candidate staging (kA)
#define PBLK 1536u              // per-block survivor staging (kSel slice size)

typedef unsigned long long ull;
typedef ull ull2 __attribute__((ext_vector_type(2)));

// Monotone float->uint key: descending float == descending key
__device__ __forceinline__ uint32_t fkey(float x) {
  uint32_t k = __float_as_uint(x);
  return (k & 0x80000000u) ? ~k : (k | 0x80000000u);
}

// Inclusive suffix sum of per-thread v across 1024 threads (3 barriers).
// part = LDS[16]; part[0] ends as grand total.
__device__ __forceinline__ uint32_t suffix_scan_1024(uint32_t v, uint32_t* part,
                                                     int t) {
  int lane = t & 63, wid = t >> 6;
#pragma unroll
  for (int off = 1; off < 64; off <<= 1) {
    uint32_t x = __shfl_down(v, off);
    if (lane + off < 64) v += x;
  }
  if (lane == 0) part[wid] = v;  // wave totals
  __syncthreads();
  if (wid == 0) {
    uint32_t pv = (lane < 16) ? part[lane] : 0u;
#pragma unroll
    for (int off = 1; off < 16; off <<= 1) {
      uint32_t x = __shfl_down(pv, off);
      if (lane + off < 16) pv += x;
    }
    if (lane < 16) part[lane] = pv;  // inclusive suffix of wave totals
  }
  __syncthreads();
  uint32_t after = (wid < 15) ? part[wid + 1] : 0u;
  return v + after;
}

// Suffix-scan hl[NBINSX] with 1024 threads, find crossing bin for `target`.
// A = count strictly above bin; cnt = hl[bin]; A < target <= A + cnt.
template <int NBINSX>
__device__ __forceinline__ void pick_bin1024(const uint32_t* hl, uint32_t target,
                                             int t, uint32_t* part,
                                             uint32_t* binS, uint32_t* AS,
                                             uint32_t* cntS) {
  const int CH = NBINSX / 1024;
  uint32_t cc[CH];
  uint32_t s = 0;
#pragma unroll
  for (int j = 0; j < CH; ++j) { cc[j] = hl[t * CH + j]; s += cc[j]; }
  uint32_t incl = suffix_scan_1024(s, part, t);
  uint32_t after = incl - s;  // suffix strictly after my chunk
  if (incl >= target && after < target) {  // crossing in my chunk: unique
    uint32_t cum = after;
    for (int j = CH - 1; j >= 0; --j) {
      if (cum + cc[j] >= target) {
        *binS = (uint32_t)(t * CH + j); *AS = cum; *cntS = cc[j]; break;
      }
      cum += cc[j];
    }
  }
}

// ---------------- kernel A: slotted stream + static compact ---------------
// Slotted output (per-block 48-slot region, plain cnt[b] store, pad keys 0)
// needs NO zeroed global counter. Block 0 zeroes sel[] for kSel's survivor
// atomic. Overflow (cnt[b] > SLOTS) detected by kSel -> full-rescan fallback.
// r10 lesson (kFG, 57us, absmax regression): do NOT fuse the tail further;
// r9's kA->kSel->kF2->kG->kH shape is the measured optimum.
__global__ void __launch_bounds__(256) kA(const float4* __restrict__ cls, int n4,
                                          uint32_t* __restrict__ sel,
                                          uint32_t* __restrict__ cnt,
                                          uint32_t* __restrict__ candKey,
                                          uint32_t* __restrict__ candIdx) {
  __shared__ uint32_t lk[LCAP];
  __shared__ uint32_t li[LCAP];
  __shared__ uint32_t lcnt;
  if (threadIdx.x == 0) lcnt = 0u;
  if (blockIdx.x == 0 && threadIdx.x < 16) sel[threadIdx.x] = 0u;
  __syncthreads();
  int stride = gridDim.x * blockDim.x;
  for (int i = blockIdx.x * blockDim.x + threadIdx.x; i < n4; i += stride) {
    float4 v = cls[i];
    float f4[4] = {v.x, v.y, v.z, v.w};
#pragma unroll
    for (int c = 0; c < 4; ++c) {
      if (f4[c] >= STATIC_F) {
        uint32_t p = atomicAdd(&lcnt, 1u);  // LDS atomic: cheap, distributed
        if (p < LCAP) { lk[p] = fkey(f4[c]); li[p] = (uint32_t)i * 4u + c; }
        // p >= LCAP: dropped, but cnt[b] records the truth -> fallback
      }
    }
  }
  __syncthreads();
  uint32_t c = lcnt;
  if (threadIdx.x == 0) cnt[blockIdx.x] = c;  // raw count; >SLOTS => overflow
  uint32_t m = c; if (m > SLOTS) m = SLOTS;
  uint32_t base = blockIdx.x * SLOTS;
  for (uint32_t i = threadIdx.x; i < SLOTS; i += 256u)
    candKey[base + i] = (i < m) ? lk[i] : 0u;   // pad keys filterable (<T)
  for (uint32_t i = threadIdx.x; i < m; i += 256u)
    candIdx[base + i] = li[i];
}

// ---------------- kernel Sel: multi-block threshold + survivor select -----
// 64 blocks x 1024 threads. Each block: read cnt[] (total+overflow),
// redundant 4096-bin LDS hist over the slot keys (24 uint4 iters, pads
// filtered), pick crossing bin, T = bin floor (TARGET slack absorbs the
// bin; bump to bin+1 on tie-spike -- block 0 then prefills), select own
// 1536-slot slice into LDS, ONE global atomic, emit srv.
// FALLBACK (overflow or total < TARGET; never on bench data): block 0 full
// 21M two-level scan + prefill + select.
__global__ void __launch_bounds__(1024) kSel(
    const float4* __restrict__ cls4, int n4,
    uint32_t* __restrict__ sel, const uint32_t* __restrict__ cnt,
    const uint32_t* __restrict__ candKey, const uint32_t* __restrict__ candIdx,
    ull* __restrict__ srv, float* __restrict__ out,
    float* __restrict__ topScore) {
  __shared__ uint32_t hl[NBINS];       // 16 KB
  __shared__ uint32_t part[16];
  __shared__ uint32_t sk_[PBLK];       // staged survivor keys (6 KB)
  __shared__ uint32_t si_[PBLK];       // staged survivor idxs (6 KB)
  __shared__ uint32_t lcnt, gbase, binS, AS, cntS, ovS;
  int t = threadIdx.x;
  uint32_t b = blockIdx.x;

  uint32_t c0 = cnt[t], c1 = cnt[t + 1024];
  if (t == 0) { lcnt = 0u; binS = 0u; AS = 0u; cntS = 0u; ovS = 0u; }
  for (int i = t; i < NBINS; i += 1024) hl[i] = 0u;
  __syncthreads();
  if (c0 > SLOTS || c1 > SLOTS) atomicOr(&ovS, 1u);
  uint32_t m0 = c0 > SLOTS ? SLOTS : c0, m1 = c1 > SLOTS ? SLOTS : c1;
  (void)suffix_scan_1024(m0 + m1, part, t);      // part[0] = total (barriers
  uint32_t total = part[0];                      //  also publish ovS)
  bool fb = (ovS != 0u) || (total < TARGET);

  if (!fb) {
    // ---- redundant hist over slot keys (coalesced, pads filtered) ----
    const uint4* ck4 = (const uint4*)candKey;
    for (uint32_t i = t; i < LINCAP / 4u; i += 1024u) {
      uint4 kv = ck4[i];
      uint32_t kk[4] = {kv.x, kv.y, kv.z, kv.w};
#pragma unroll
      for (int q = 0; q < 4; ++q) {
        uint32_t k = kk[q];
        if (k >= STATIC_KEY) {
          uint32_t bb = (k - STATIC_KEY) >> BINSH;
          if (bb > NBINS - 1u) bb = NBINS - 1u;
          atomicAdd(&hl[bb], 1u);
        }
      }
    }
    __syncthreads();
    pick_bin1024<NBINS>(hl, TARGET, t, part, &binS, &AS, &cntS);
    __syncthreads();
    bool bump = (AS + cntS > SRVCAP);  // tie-spike (adversarial only)
    uint32_t T = STATIC_KEY + ((binS + (bump ? 1u : 0u)) << BINSH);
    if (bump && b == 0) {              // scount may drop below TOPK: prefill
      for (int i = t; i < 4000; i += 1024) out[i] = 0.0f;
      for (int i = t; i < 1000; i += 1024) { out[5000 + i] = 0.0f; topScore[i] = 0.0f; }
    }
    // ---- select own contiguous slice of slots ----
    uint32_t lo = b * (LINCAP / 64u), hi = lo + (LINCAP / 64u);  // 1536
    for (uint32_t i = lo + t; i < hi; i += 1024u) {
      uint32_t k = candKey[i];
      if (k >= T) {                    // pads (0) auto-excluded
        uint32_t p = atomicAdd(&lcnt, 1u);
        sk_[p] = k; si_[p] = candIdx[i];  // p < PBLK == slice size: safe
      }
    }
    __syncthreads();
    uint32_t c = lcnt;
    if (t == 0 && c) gbase = atomicAdd(&sel[4], c);  // ONE per block
    __syncthreads();
    for (uint32_t i = t; i < c; i += 1024u) {
      uint32_t k = sk_[i];
      float x = __uint_as_float(k & 0x7fffffffu);  // candidates all positive
      float p = 1.0f / (1.0f + expf(-x));          // fp32 sigmoid
      uint32_t pos = gbase + i;
      if (pos < SRVCAP)
        srv[pos] = ((ull)__float_as_uint(p) << 32) | (ull)(uint32_t)(~si_[i]);
    }
  } else {
    if (b != 0) return;
    // ---- single-block full fallback (perf-irrelevant) ----
    for (int i = t; i < NBINS; i += 1024) hl[i] = 0u;
    if (t == 0) { binS = 0u; AS = 0u; cntS = 0u; }
    __syncthreads();
    for (int i = t; i < n4; i += 1024) {
      float4 v = cls4[i];
      atomicAdd(&hl[fkey(v.x) >> 20], 1u);
      atomicAdd(&hl[fkey(v.y) >> 20], 1u);
      atomicAdd(&hl[fkey(v.z) >> 20], 1u);
      atomicAdd(&hl[fkey(v.w) >> 20], 1u);
    }
    __syncthreads();
    pick_bin1024<NBINS>(hl, TARGET, t, part, &binS, &AS, &cntS);  // k>>20
    __syncthreads();
    uint32_t b20 = binS, A = AS;
    hl[t] = 0u;
    if (t == 0) binS = 0u;
    __syncthreads();
    for (int i = t; i < n4; i += 1024) {  // fine 10-bit hist within b20
      float4 v = cls4[i];
      uint32_t k4[4] = {fkey(v.x), fkey(v.y), fkey(v.z), fkey(v.w)};
#pragma unroll
      for (int c2 = 0; c2 < 4; ++c2)
        if ((k4[c2] >> 20) == b20) atomicAdd(&hl[(k4[c2] >> 10) & 1023u], 1u);
    }
    __syncthreads();
    uint32_t rem = TARGET - A;  // >= 1; fine total >= rem
    pick_bin1024<1024>(hl, rem, t, part, &binS, &AS, &cntS);
    __syncthreads();
    uint32_t T = (b20 << 20) | (binS << 10);
    for (int i = t; i < 4000; i += 1024) out[i] = 0.0f;   // prefill
    for (int i = t; i < 1000; i += 1024) { out[5000 + i] = 0.0f; topScore[i] = 0.0f; }
    for (int i = t; i < n4; i += 1024) {
      float4 v = cls4[i];
      uint32_t k4[4] = {fkey(v.x), fkey(v.y), fkey(v.z), fkey(v.w)};
#pragma unroll
      for (int c2 = 0; c2 < 4; ++c2) {
        uint32_t k = k4[c2];
        if (k >= T) {
          uint32_t pos = atomicAdd(&sel[4], 1u);
          if (pos < SRVCAP) {
            float x = (k & 0x80000000u) ? __uint_as_float(k & 0x7fffffffu)
                                        : __uint_as_float(~k);
            float p = 1.0f / (1.0f + expf(-x));
            uint32_t idx = (uint32_t)i * 4u + c2;
            srv[pos] = ((ull)__float_as_uint(p) << 32) | (ull)(uint32_t)(~idx);
          }
        }
      }
    }
  }
}

// ---------------- kernel F2: rank survivors + emit ------------------------
// 8 blocks x 256. Thread i ranks ONLY its own survivor (r10 lesson: full
// redundant ranking multiplies per-block LDS serial work 8x -> 57us).
// Boxes emitted straight from box[] (no +off/-off round-trip: exact).
__global__ void __launch_bounds__(256) kF2(
    const float* __restrict__ box, const int* __restrict__ ph,
    const int* __restrict__ pw, const uint32_t* __restrict__ sel,
    const ull* __restrict__ srv, float* __restrict__ out,
    float* __restrict__ topScore, float* __restrict__ obox) {
  __shared__ __align__(16) ull sk[SRVCAP];
  int t = threadIdx.x;
  uint32_t scount = sel[4]; if (scount > SRVCAP) scount = SRVCAP;
  uint32_t pad = (scount + 1u) & ~1u;
  for (uint32_t i = t; i < pad; i += 256u) sk[i] = (i < scount) ? srv[i] : 0ull;
  __syncthreads();
  uint32_t i = blockIdx.x * 256u + (uint32_t)t;
  if (i >= scount) return;
  ull my = sk[i];
  uint32_t rank = 0;
#pragma unroll 4
  for (uint32_t j = 0; j < pad; j += 2u) {
    ull2 v = *reinterpret_cast<const ull2*>(&sk[j]);  // b128 broadcast read
    rank += (v.x > my) + (v.y > my);
  }
  if (rank >= TOPK) return;
  uint32_t idx = ~(uint32_t)my;
  float p = __uint_as_float((uint32_t)(my >> 32));
  uint32_t label = idx % NUM_CLASSES;
  uint32_t anchor = idx / NUM_CLASSES;
  float W = (float)pw[0], H = (float)ph[0];
  float b0 = box[anchor * 4u + 0u], b1 = box[anchor * 4u + 1u];
  float b2 = box[anchor * 4u + 2u], b3 = box[anchor * 4u + 3u];
  out[rank * 4 + 0] = fminf(fmaxf(b0 / W, 0.0f), 1.0f);
  out[rank * 4 + 1] = fminf(fmaxf(b1 / H, 0.0f), 1.0f);
  out[rank * 4 + 2] = fminf(fmaxf(b2 / W, 0.0f), 1.0f);
  out[rank * 4 + 3] = fminf(fmaxf(b3 / H, 0.0f), 1.0f);
  out[5000 + rank] = (float)label;
  topScore[rank] = p;
  float off = (float)label * MAX_COORD;  // class-aware NMS offset
  obox[rank * 4 + 0] = b0 + off; obox[rank * 4 + 1] = b1 + off;
  obox[rank * 4 + 2] = b2 + off; obox[rank * 4 + 3] = b3 + off;
}

// ---------------- kernel G: IoU bitmasks (j > i) + per-row summary --------
// rowsum[i] bit g = (mask word g of row i nonzero). Lets kH skip staging
// the ~90% of the 128 KB mask matrix that is all-zero.
__global__ void kG(const float* __restrict__ obox, ull* __restrict__ masks,
                   uint32_t* __restrict__ rowsum) {
  __shared__ uint32_t rsS;
  int i = blockIdx.x;  // row 0..999
  if (threadIdx.x == 0) rsS = 0u;
  __syncthreads();
  float x1i = obox[i * 4 + 0], y1i = obox[i * 4 + 1];
  float x2i = obox[i * 4 + 2], y2i = obox[i * 4 + 3];
  float ai = (x2i - x1i) * (y2i - y1i);
  for (int base = 0; base < 1024; base += 256) {
    int jj = base + (int)threadIdx.x;
    bool bit = false;
    if (jj < TOPK && jj > i) {
      float x1j = obox[jj * 4 + 0], y1j = obox[jj * 4 + 1];
      float x2j = obox[jj * 4 + 2], y2j = obox[jj * 4 + 3];
      float aj = (x2j - x1j) * (y2j - y1j);
      float ix1 = fmaxf(x1i, x1j), iy1 = fmaxf(y1i, y1j);
      float ix2 = fminf(x2i, x2j), iy2 = fminf(y2i, y2j);
      float iw = fmaxf(ix2 - ix1, 0.0f), ih = fmaxf(iy2 - iy1, 0.0f);
      float inter = iw * ih;
      float iou = inter / (ai + aj - inter + 1e-9f);
      bit = iou > NMS_T;
    }
    ull m = __ballot(bit);
    if ((threadIdx.x & 63u) == 0u) {
      masks[i * 16 + (jj >> 6)] = m;
      if (m) atomicOr(&rsS, 1u << (jj >> 6));
    }
  }
  __syncthreads();
  if (threadIdx.x == 0) rowsum[i] = rsS;
}

// ---------------- kernel H: LDS-staged single-wave greedy NMS -------------
// 1024 threads; stages only rowsum-flagged mask words.
__global__ void __launch_bounds__(1024) kH(const float* __restrict__ topScore,
                                           const ull* __restrict__ masks,
                                           const uint32_t* __restrict__ rowsum,
                                           float* __restrict__ out) {
  __shared__ ull lmask[TOPK * 16];
  __shared__ uint32_t rsL[TOPK];
  __shared__ ull keepsh[16];
  int t = threadIdx.x;
  if (t < TOPK) rsL[t] = rowsum[t];
  if (t < 16) keepsh[t] = 0ull;
  __syncthreads();
  for (int i = t; i < TOPK * 16; i += 1024)  // stage only nonzero words
    lmask[i] = ((rsL[i >> 4] >> (i & 15)) & 1u) ? masks[i] : 0ull;
  {
    bool v = (t < TOPK) && (topScore[t] > CONF_T);
    ull bb = __ballot(v);
    if ((t & 63) == 0) keepsh[t >> 6] = bb;
  }
  __syncthreads();
  if (t < 64) {  // single-wave greedy loop, no barriers inside
    ull kw = (t < 16) ? keepsh[t] : 0ull;
    ull nzw = 0ull;
    if (t < 16) {
      for (int b = 0; b < 64; ++b) {
        int r = t * 64 + b;
        if (r < TOPK && rsL[r]) nzw |= 1ull << b;
      }
    }
    for (int w = 0; w < 16; ++w) {
      ull cur = __shfl(kw, w) & __shfl(nzw, w);
      while (cur) {
        int b = __ffsll((long long)cur) - 1;
        int i = w * 64 + b;
        if (t < 16) kw &= ~lmask[i * 16 + t];  // row i suppresses only j > i
        ull nk = __shfl(kw, w);
        cur = nk & __shfl(nzw, w);
        cur &= (b == 63) ? 0ull : (~0ull << (b + 1));
      }
    }
    if (t < 16) keepsh[t] = kw;
  }
  __syncthreads();
  if (t < TOPK) {
    bool k = (keepsh[t >> 6] >> (t & 63)) & 1ull;
    float s = topScore[t];
    out[4000 + t] = k ? s : 0.0f;
    out[6000 + t] = k ? 1.0f : 0.0f;
  }
}

extern "C" void kernel_launch(void* const* d_in, const int* in_sizes, int n_in,
                              void* d_out, int out_size, void* d_ws, size_t ws_size,
                              hipStream_t stream) {
  const float* cls = (const float*)d_in[0];  // (1, N, 80) logits
  const float* box = (const float*)d_in[1];  // (1, N, 4)
  const int* ph = (const int*)d_in[2];       // img_h
  const int* pw = (const int*)d_in[3];       // img_w
  float* out = (float*)d_out;                // [boxes 4000 | scores 1000 | labels 1000 | keep 1000]
  int n = in_sizes[0];                       // 20,971,520 (divisible by 4)

  uint8_t* w = (uint8_t*)d_ws;
  uint32_t* cnt     = (uint32_t*)(w);                               // 8 KB
  uint32_t* sel     = (uint32_t*)(w + 8192);                        // 64 B (pad 4 KB)
  uint32_t* candKey = (uint32_t*)(w + 12288);                       // 384 KB
  uint32_t* candIdx = (uint32_t*)(w + 12288 + (size_t)LINCAP * 4);  // 384 KB
  ull*      srv     = (ull*)     (w + 12288 + (size_t)LINCAP * 8);  // 16 KB
  float*    topScore= (float*)   (w + 12288 + (size_t)LINCAP * 8 + 16384);          // 4 KB
  float*    obox    = (float*)   (w + 12288 + (size_t)LINCAP * 8 + 16384 + 4096);   // 16 KB
  ull*      masks   = (ull*)     (w + 12288 + (size_t)LINCAP * 8 + 16384 + 4096 + 16384); // 128 KB
  uint32_t* rowsum  = (uint32_t*)(w + 12288 + (size_t)LINCAP * 8 + 16384 + 4096 + 16384 + 131072); // 4 KB

  kA  <<<NBLK_A, 256, 0, stream>>>((const float4*)cls, n / 4, sel, cnt, candKey, candIdx);
  kSel<<<64, 1024, 0, stream>>>((const float4*)cls, n / 4, sel, cnt, candKey, candIdx, srv, out, topScore);
  kF2 <<<SRVCAP / 256, 256, 0, stream>>>(box, ph, pw, sel, srv, out, topScore, obox);
  kG  <<<TOPK, 256, 0, stream>>>(obox, masks, rowsum);
  kH  <<<1, 1024, 0, stream>>>(topScore, masks, rowsum, out);
}